// Round 12
// baseline (508.448 us; speedup 1.0000x reference)
//
#include <hip/hip_runtime.h>
#include <math.h>

#define B2 2
#define HW 4096
#define L4 4096
#define NCH 64          // chunks for the scan (CLEN = 64)

// ---------------- workspace offsets (floats) ----------------
enum : size_t {
  OFF_APROD  = 0,         // 16384*64 = 1048576, lives only during scan (region dead then)
  OFF_HEND   = 1048576,   // 1048576
  OFF_SSTART = 2097152,   // 1048576, ends 3145728
  OFF_INP    = 0,
  OFF_SHORT  = 524288,
  OFF_RSHUF  = 7118848,   // padded [B][66][66][66]; overlays XC2 region (dead during res branch)
  OFF_XLN    = 2129920,   // reused as xln2 later
  OFF_SRAW   = 2654208,
  OFF_SRED   = 2920448,
  OFF_QT     = 3186688,
  OFF_KT     = 3710976,
  OFF_VT     = 3842048,
  OFF_OT     = 3973120,
  OFF_M0     = 4497408,
  OFF_XC     = 3186688,   // overlays qt/kt/vt/ot (dead by then)
  OFF_U1     = 0,         // overlays inp + scan summaries (dead by then)
  OFF_T      = 5021696,
  OFF_T1     = 5545984,
  OFF_Z      = 6070272,
  OFF_XC2    = 7118848,
  OFF_XC2T   = 8167424,
  OFF_PROJ   = 9216000,
  OFF_YM     = 11182080,  // ym accumulator, then g (in-place)
  OFF_PART   = 7118848,   // attention partials (8 ktiles x 18), overlays xc2/xc2t/proj/ym head (dead during attn)
};

#define RS_CH 4356   // 66*66 padded spatial
#define RS_B  287496 // 66*4356

// ---------------- res branch: 1x1 conv + mean/max + channel shuffle -> PADDED rshuf ----------------
__global__ void k_rconv0(const float* __restrict__ res, const float* __restrict__ rc0_w,
                         float* __restrict__ rshufP) {
  int idx = blockIdx.x * 256 + threadIdx.x;
  if (idx >= B2 * 66 * HW) return;
  int p = idx & (HW - 1);
  int bc = idx >> 12;
  int c = bc % 66, b = bc / 66;
  int cc = (c % 22) * 3 + (c / 22);     // inverse of channel shuffle
  const float* rb = res + (size_t)b * 32 * HW + p;
  float v;
  if (cc < 64) {
    const float* w = rc0_w + cc * 32;
    float a = 0.f;
#pragma unroll
    for (int ic = 0; ic < 32; ++ic) a = fmaf(w[ic], rb[ic * HW], a);
    v = a;
  } else if (cc == 64) {
    float s = 0.f;
#pragma unroll
    for (int ic = 0; ic < 32; ++ic) s += rb[ic * HW];
    v = s * (1.f / 32.f);
  } else {
    float m = rb[0];
#pragma unroll
    for (int ic = 1; ic < 32; ++ic) m = fmaxf(m, rb[ic * HW]);
    v = m;
  }
  int h = p >> 6, w = p & 63;
  rshufP[(size_t)(b * 66 + c) * RS_CH + (h + 1) * 66 + (w + 1)] = v;
}

// ---------------- 3x3 conv 66->66 + BN + relu6 -> shortcut[0:66] ----------------
__global__ __launch_bounds__(256) void k_rconv3(const float* __restrict__ rshufP,
                                                const float* __restrict__ rcp_w,
                                                const float* __restrict__ rcp_g,
                                                const float* __restrict__ rcp_b,
                                                float* __restrict__ shortcut) {
  __shared__ float lw[3 * 594];
  int cg = blockIdx.y % 22, b = blockIdx.y / 22;
  int c0 = cg * 3;
  for (int i = threadIdx.x; i < 3 * 594; i += 256) lw[i] = rcp_w[c0 * 594 + i];
  __syncthreads();
  int p = blockIdx.x * 256 + threadIdx.x;
  int h = p >> 6, w = p & 63;
  const float* base = rshufP + (size_t)b * RS_B + h * 66 + w;
  float a0 = 0.f, a1 = 0.f, a2 = 0.f;
#pragma unroll 2
  for (int ci = 0; ci < 66; ++ci) {
    const float* ib = base + (size_t)ci * RS_CH;
    float x0 = ib[0],   x1 = ib[1],   x2 = ib[2];
    float x3 = ib[66],  x4 = ib[67],  x5 = ib[68];
    float x6 = ib[132], x7 = ib[133], x8 = ib[134];
    const float* q0 = lw + ci * 9;
    const float* q1 = lw + 594 + ci * 9;
    const float* q2 = lw + 1188 + ci * 9;
    a0 = fmaf(q0[0], x0, fmaf(q0[1], x1, fmaf(q0[2], x2, fmaf(q0[3], x3, fmaf(q0[4], x4,
         fmaf(q0[5], x5, fmaf(q0[6], x6, fmaf(q0[7], x7, fmaf(q0[8], x8, a0)))))))));
    a1 = fmaf(q1[0], x0, fmaf(q1[1], x1, fmaf(q1[2], x2, fmaf(q1[3], x3, fmaf(q1[4], x4,
         fmaf(q1[5], x5, fmaf(q1[6], x6, fmaf(q1[7], x7, fmaf(q1[8], x8, a1)))))))));
    a2 = fmaf(q2[0], x0, fmaf(q2[1], x1, fmaf(q2[2], x2, fmaf(q2[3], x3, fmaf(q2[4], x4,
         fmaf(q2[5], x5, fmaf(q2[6], x6, fmaf(q2[7], x7, fmaf(q2[8], x8, a2)))))))));
  }
  const float bscale = rsqrtf(1.f + 1e-5f);
  float acc[3] = {a0, a1, a2};
#pragma unroll
  for (int u = 0; u < 3; ++u) {
    int co = c0 + u;
    float v = acc[u] * (rcp_g[co] * bscale) + rcp_b[co];
    v = fminf(fmaxf(v, 0.f), 6.f);
    shortcut[(size_t)(b * 130 + co) * HW + p] = v;
  }
}

// ---------------- bilinear 2x upsample: smf -> shortcut[66:130], x -> inp ----------------
__global__ void k_up(const float* __restrict__ smf, const float* __restrict__ x,
                     float* __restrict__ shortcut, float* __restrict__ inp) {
  int idx = blockIdx.x * 256 + threadIdx.x;
  if (idx >= B2 * 128 * HW) return;
  int p = idx & (HW - 1);
  int bc = idx >> 12;
  int c = bc & 127, b = bc >> 7;
  int oh = p >> 6, ow = p & 63;
  int hp = oh >> 1, wp = ow >> 1;
  int ih0, ih1, iw0, iw1;
  float wh0, ww0;
  if (oh & 1) { ih0 = hp; ih1 = (hp + 1 > 31) ? 31 : hp + 1; wh0 = 0.75f; }
  else        { ih0 = (hp - 1 < 0) ? 0 : hp - 1; ih1 = hp; wh0 = 0.25f; }
  if (ow & 1) { iw0 = wp; iw1 = (wp + 1 > 31) ? 31 : wp + 1; ww0 = 0.75f; }
  else        { iw0 = (wp - 1 < 0) ? 0 : wp - 1; iw1 = wp; ww0 = 0.25f; }
  const float* src = (c < 64) ? (smf + (size_t)(b * 64 + c) * 1024)
                              : (x + (size_t)(b * 64 + (c - 64)) * 1024);
  float v00 = src[ih0 * 32 + iw0], v01 = src[ih0 * 32 + iw1];
  float v10 = src[ih1 * 32 + iw0], v11 = src[ih1 * 32 + iw1];
  float v = wh0 * (ww0 * v00 + (1.f - ww0) * v01) + (1.f - wh0) * (ww0 * v10 + (1.f - ww0) * v11);
  if (c < 64) shortcut[(size_t)(b * 130 + 66 + c) * HW + p] = v;
  else        inp[(size_t)(b * 64 + (c - 64)) * HW + p] = v;
}

// ---------------- t = inp + dwconv3x3(inp) + pe_b ----------------
__global__ void k_pe(const float* __restrict__ inp, const float* __restrict__ pe_w,
                     const float* __restrict__ pe_b, float* __restrict__ t) {
  int idx = blockIdx.x * 256 + threadIdx.x;
  if (idx >= B2 * 64 * HW) return;
  int p = idx & (HW - 1);
  int bc = idx >> 12;
  int c = bc & 63;
  int h = p >> 6, w = p & 63;
  const float* ib = inp + (size_t)bc * HW;
  const float* wt = pe_w + c * 9;
  float a = pe_b[c];
#pragma unroll
  for (int kh = -1; kh <= 1; ++kh) {
    int hh = h + kh;
    if (hh < 0 || hh > 63) continue;
#pragma unroll
    for (int kw = -1; kw <= 1; ++kw) {
      int ww = w + kw;
      if (ww < 0 || ww > 63) continue;
      a = fmaf(wt[(kh + 1) * 3 + (kw + 1)], ib[hh * 64 + ww], a);
    }
  }
  t[idx] = ib[p] + a;
}

// ---------------- LayerNorm over 64 channels (NCHW), widened: 128 blocks ----------------
__global__ __launch_bounds__(256) void k_lnc64(const float* __restrict__ in,
                                               const float* __restrict__ g,
                                               const float* __restrict__ bb,
                                               float* __restrict__ out) {
  __shared__ float sred[2][4][64];
  int tid = threadIdx.x;
  int pos = tid & 63, cq = tid >> 6;        // 4 channel-quarters
  int gp = blockIdx.x * 64 + pos;           // global position
  int p = gp & (HW - 1), b = gp >> 12;
  const float* ib = in + (size_t)b * 64 * HW + p;
  float s = 0.f, sq = 0.f;
#pragma unroll
  for (int i = 0; i < 16; ++i) {
    float v = ib[(cq * 16 + i) * HW];
    s += v; sq = fmaf(v, v, sq);
  }
  sred[0][cq][pos] = s;
  sred[1][cq][pos] = sq;
  __syncthreads();
  float S  = sred[0][0][pos] + sred[0][1][pos] + sred[0][2][pos] + sred[0][3][pos];
  float SQ = sred[1][0][pos] + sred[1][1][pos] + sred[1][2][pos] + sred[1][3][pos];
  float mu = S * (1.f / 64.f);
  float var = SQ * (1.f / 64.f) - mu * mu;
  float rs = rsqrtf(var + 1e-5f);
  float* ob = out + (size_t)b * 64 * HW + p;
#pragma unroll
  for (int i = 0; i < 16; ++i) {
    int c = cq * 16 + i;
    ob[c * HW] = (ib[c * HW] - mu) * rs * g[c] + bb[c];
  }
}

// ---------------- 2x2 stride-2 conv 130->130 + bias ----------------
__global__ __launch_bounds__(256) void k_sr(const float* __restrict__ shortcut,
                                            const float* __restrict__ sr_w,
                                            const float* __restrict__ sr_b,
                                            float* __restrict__ sraw) {
  __shared__ float lw[5 * 520];
  int cg = blockIdx.y % 26, b = blockIdx.y / 26;
  int c0 = cg * 5;
  for (int i = threadIdx.x; i < 5 * 520; i += 256) lw[i] = sr_w[c0 * 520 + i];
  __syncthreads();
  int op = blockIdx.x * 256 + threadIdx.x;
  int oh = op >> 5, ow = op & 31;
  const float* ib = shortcut + (size_t)b * 130 * HW + (oh * 2) * 64 + ow * 2;
  float acc[5] = {0, 0, 0, 0, 0};
  for (int ci = 0; ci < 130; ++ci) {
    const float* q = ib + (size_t)ci * HW;
    float x00 = q[0], x01 = q[1], x10 = q[64], x11 = q[65];
#pragma unroll
    for (int u = 0; u < 5; ++u) {
      const float* wp = lw + u * 520 + ci * 4;
      acc[u] = fmaf(wp[0], x00, fmaf(wp[1], x01, fmaf(wp[2], x10, fmaf(wp[3], x11, acc[u]))));
    }
  }
#pragma unroll
  for (int u = 0; u < 5; ++u)
    sraw[(size_t)(b * 130 + c0 + u) * 1024 + op] = acc[u] + sr_b[c0 + u];
}

// ---------------- LayerNorm over 130 channels ----------------
__global__ __launch_bounds__(64) void k_ln130(const float* __restrict__ sraw,
                                              const float* __restrict__ g,
                                              const float* __restrict__ bb,
                                              float* __restrict__ sred) {
  int op = blockIdx.x & 1023, b = blockIdx.x >> 10;
  int t = threadIdx.x;
  const float* ib = sraw + (size_t)b * 130 * 1024 + op;
  float s = 0.f, sq = 0.f;
  for (int c = t; c < 130; c += 64) { float v = ib[c * 1024]; s += v; sq = fmaf(v, v, sq); }
#pragma unroll
  for (int off = 32; off; off >>= 1) { s += __shfl_xor(s, off); sq += __shfl_xor(sq, off); }
  float mu = s * (1.f / 130.f);
  float var = sq * (1.f / 130.f) - mu * mu;
  float rs = rsqrtf(var + 1e-5f);
  float* ob = sred + (size_t)b * 130 * 1024 + op;
  for (int c = t; c < 130; c += 64) ob[c * 1024] = (ib[c * 1024] - mu) * rs * g[c] + bb[c];
}

// ---------------- k/v 1x1 convs (130 -> 64 each), layout (b,h,key,16) ----------------
__global__ void k_kv(const float* __restrict__ sred, const float* __restrict__ k_w,
                     const float* __restrict__ k_b, const float* __restrict__ v_w,
                     const float* __restrict__ v_b, float* __restrict__ kt, float* __restrict__ vt) {
  int idx = blockIdx.x * 256 + threadIdx.x;
  if (idx >= B2 * 128 * 1024) return;
  int op = idx & 1023;
  int bc = idx >> 10;
  int c = bc & 127, b = bc >> 7;
  bool isv = c >= 64;
  int co = c & 63;
  const float* w = (isv ? v_w : k_w) + co * 130;
  const float* ib = sred + (size_t)b * 130 * 1024 + op;
  float a = (isv ? v_b : k_b)[co];
  for (int ci = 0; ci < 130; ++ci) a = fmaf(w[ci], ib[ci * 1024], a);
  float* dst = isv ? vt : kt;
  dst[((size_t)(b * 4 + (co >> 4)) * 1024 + op) * 16 + (co & 15)] = a;
}

// ---------------- q 1x1 conv, layout (b,h,p,16) ----------------
__global__ void k_q(const float* __restrict__ xln, const float* __restrict__ q_w,
                    const float* __restrict__ q_b, float* __restrict__ qt) {
  int idx = blockIdx.x * 256 + threadIdx.x;
  if (idx >= B2 * 64 * HW) return;
  int p = idx & (HW - 1);
  int bc = idx >> 12;
  int co = bc & 63, b = bc >> 6;
  const float* ib = xln + (size_t)b * 64 * HW + p;
  const float* w = q_w + co * 64;
  float a = q_b[co];
#pragma unroll
  for (int ci = 0; ci < 64; ++ci) a = fmaf(w[ci], ib[ci * HW], a);
  qt[((size_t)(b * 4 + (co >> 4)) * HW + p) * 16 + (co & 15)] = a;
}

// ---------------- flash attention phase 1 v3: 2 q/thread, ktile=128, ILP + prefetch ----------------
// grid (8 ktile, 8 qtile, 8 bh) = 512 blocks. 4-partial dots + register prefetch of next K/V.
__global__ __launch_bounds__(256) void k_attn1(const float* __restrict__ qt,
                                               const float* __restrict__ kt,
                                               const float* __restrict__ vt,
                                               float* __restrict__ part) {
  __shared__ float sk[128 * 16];
  __shared__ float sv[128 * 16];
  int ktile = blockIdx.x, qtile = blockIdx.y, bh = blockIdx.z;
  int tid = threadIdx.x;
  const float* kb = kt + ((size_t)bh * 1024 + ktile * 128) * 16;
  const float* vb = vt + ((size_t)bh * 1024 + ktile * 128) * 16;
  for (int i = tid * 4; i < 2048; i += 1024) {
    *(float4*)&sk[i] = *(const float4*)&kb[i];
    *(float4*)&sv[i] = *(const float4*)&vb[i];
  }
  __syncthreads();
  int qa = qtile * 512 + tid;
  int qb = qa + 256;
  const float sc = 0.25f;
  const float4* qra = (const float4*)(qt + ((size_t)bh * HW + qa) * 16);
  float4 a0 = qra[0], a1 = qra[1], a2 = qra[2], a3 = qra[3];
  a0.x *= sc; a0.y *= sc; a0.z *= sc; a0.w *= sc;
  a1.x *= sc; a1.y *= sc; a1.z *= sc; a1.w *= sc;
  a2.x *= sc; a2.y *= sc; a2.z *= sc; a2.w *= sc;
  a3.x *= sc; a3.y *= sc; a3.z *= sc; a3.w *= sc;
  const float4* qrb = (const float4*)(qt + ((size_t)bh * HW + qb) * 16);
  float4 b0 = qrb[0], b1 = qrb[1], b2 = qrb[2], b3 = qrb[3];
  b0.x *= sc; b0.y *= sc; b0.z *= sc; b0.w *= sc;
  b1.x *= sc; b1.y *= sc; b1.z *= sc; b1.w *= sc;
  b2.x *= sc; b2.y *= sc; b2.z *= sc; b2.w *= sc;
  b3.x *= sc; b3.y *= sc; b3.z *= sc; b3.w *= sc;
  float ma = -1e30f, la = 0.f, mb = -1e30f, lb = 0.f;
  float acca[16], accb[16];
#pragma unroll
  for (int i = 0; i < 16; ++i) { acca[i] = 0.f; accb[i] = 0.f; }
  // preload key 0
  float4 k0 = ((const float4*)sk)[0], k1 = ((const float4*)sk)[1],
         k2 = ((const float4*)sk)[2], k3 = ((const float4*)sk)[3];
  float4 v0 = ((const float4*)sv)[0], v1 = ((const float4*)sv)[1],
         v2 = ((const float4*)sv)[2], v3 = ((const float4*)sv)[3];
  for (int kk = 0; kk < 128; ++kk) {
    // prefetch next key's K/V while computing current
    int nx = ((kk + 1) & 127) * 4;
    float4 nk0 = ((const float4*)sk)[nx], nk1 = ((const float4*)sk)[nx + 1],
           nk2 = ((const float4*)sk)[nx + 2], nk3 = ((const float4*)sk)[nx + 3];
    float4 nv0 = ((const float4*)sv)[nx], nv1 = ((const float4*)sv)[nx + 1],
           nv2 = ((const float4*)sv)[nx + 2], nv3 = ((const float4*)sv)[nx + 3];
    // 4 independent partials per dot
    float sa0 = fmaf(a0.x, k0.x, fmaf(a0.y, k0.y, fmaf(a0.z, k0.z, a0.w * k0.w)));
    float sa1 = fmaf(a1.x, k1.x, fmaf(a1.y, k1.y, fmaf(a1.z, k1.z, a1.w * k1.w)));
    float sa2 = fmaf(a2.x, k2.x, fmaf(a2.y, k2.y, fmaf(a2.z, k2.z, a2.w * k2.w)));
    float sa3 = fmaf(a3.x, k3.x, fmaf(a3.y, k3.y, fmaf(a3.z, k3.z, a3.w * k3.w)));
    float sb0 = fmaf(b0.x, k0.x, fmaf(b0.y, k0.y, fmaf(b0.z, k0.z, b0.w * k0.w)));
    float sb1 = fmaf(b1.x, k1.x, fmaf(b1.y, k1.y, fmaf(b1.z, k1.z, b1.w * k1.w)));
    float sb2 = fmaf(b2.x, k2.x, fmaf(b2.y, k2.y, fmaf(b2.z, k2.z, b2.w * k2.w)));
    float sb3 = fmaf(b3.x, k3.x, fmaf(b3.y, k3.y, fmaf(b3.z, k3.z, b3.w * k3.w)));
    float sa = (sa0 + sa1) + (sa2 + sa3);
    float sb = (sb0 + sb1) + (sb2 + sb3);
    if (sa > ma) {
      float r = __expf(ma - sa);
      la *= r;
#pragma unroll
      for (int i = 0; i < 16; ++i) acca[i] *= r;
      ma = sa;
    }
    if (sb > mb) {
      float r = __expf(mb - sb);
      lb *= r;
#pragma unroll
      for (int i = 0; i < 16; ++i) accb[i] *= r;
      mb = sb;
    }
    float pa = __expf(sa - ma);
    float pb = __expf(sb - mb);
    la += pa; lb += pb;
    acca[0] = fmaf(pa, v0.x, acca[0]);  accb[0] = fmaf(pb, v0.x, accb[0]);
    acca[1] = fmaf(pa, v0.y, acca[1]);  accb[1] = fmaf(pb, v0.y, accb[1]);
    acca[2] = fmaf(pa, v0.z, acca[2]);  accb[2] = fmaf(pb, v0.z, accb[2]);
    acca[3] = fmaf(pa, v0.w, acca[3]);  accb[3] = fmaf(pb, v0.w, accb[3]);
    acca[4] = fmaf(pa, v1.x, acca[4]);  accb[4] = fmaf(pb, v1.x, accb[4]);
    acca[5] = fmaf(pa, v1.y, acca[5]);  accb[5] = fmaf(pb, v1.y, accb[5]);
    acca[6] = fmaf(pa, v1.z, acca[6]);  accb[6] = fmaf(pb, v1.z, accb[6]);
    acca[7] = fmaf(pa, v1.w, acca[7]);  accb[7] = fmaf(pb, v1.w, accb[7]);
    acca[8] = fmaf(pa, v2.x, acca[8]);  accb[8] = fmaf(pb, v2.x, accb[8]);
    acca[9] = fmaf(pa, v2.y, acca[9]);  accb[9] = fmaf(pb, v2.y, accb[9]);
    acca[10] = fmaf(pa, v2.z, acca[10]); accb[10] = fmaf(pb, v2.z, accb[10]);
    acca[11] = fmaf(pa, v2.w, acca[11]); accb[11] = fmaf(pb, v2.w, accb[11]);
    acca[12] = fmaf(pa, v3.x, acca[12]); accb[12] = fmaf(pb, v3.x, accb[12]);
    acca[13] = fmaf(pa, v3.y, acca[13]); accb[13] = fmaf(pb, v3.y, accb[13]);
    acca[14] = fmaf(pa, v3.z, acca[14]); accb[14] = fmaf(pb, v3.z, accb[14]);
    acca[15] = fmaf(pa, v3.w, acca[15]); accb[15] = fmaf(pb, v3.w, accb[15]);
    k0 = nk0; k1 = nk1; k2 = nk2; k3 = nk3;
    v0 = nv0; v1 = nv1; v2 = nv2; v3 = nv3;
  }
  float* oa = part + (((size_t)bh * 8 + ktile) * HW + qa) * 18;
#pragma unroll
  for (int i = 0; i < 16; ++i) oa[i] = acca[i];
  oa[16] = ma;
  oa[17] = la;
  float* ob = part + (((size_t)bh * 8 + ktile) * HW + qb) * 18;
#pragma unroll
  for (int i = 0; i < 16; ++i) ob[i] = accb[i];
  ob[16] = mb;
  ob[17] = lb;
}

// ---------------- flash attention phase 2: merge 8 ktile partials ----------------
__global__ void k_attn2(const float* __restrict__ part, float* __restrict__ ot) {
  int idx = blockIdx.x * 256 + threadIdx.x;
  if (idx >= B2 * 4 * HW) return;
  int q = idx & (HW - 1), bh = idx >> 12;
  float M = -1e30f;
#pragma unroll
  for (int kt8 = 0; kt8 < 8; ++kt8)
    M = fmaxf(M, part[(((size_t)bh * 8 + kt8) * HW + q) * 18 + 16]);
  float L = 0.f;
  float o[16];
#pragma unroll
  for (int i = 0; i < 16; ++i) o[i] = 0.f;
#pragma unroll
  for (int kt8 = 0; kt8 < 8; ++kt8) {
    const float* p = part + (((size_t)bh * 8 + kt8) * HW + q) * 18;
    float w = __expf(p[16] - M);
    L = fmaf(p[17], w, L);
#pragma unroll
    for (int i = 0; i < 16; ++i) o[i] = fmaf(p[i], w, o[i]);
  }
  float inv = 1.f / L;
  float* ob = ot + ((size_t)bh * HW + q) * 16;
#pragma unroll
  for (int i = 0; i < 16; ++i) ob[i] = o[i] * inv;
}

// ---------------- mp 1x1 conv -> m0 (NCHW) ----------------
__global__ void k_mp(const float* __restrict__ ot, const float* __restrict__ mp_w,
                     const float* __restrict__ mp_b, float* __restrict__ m0) {
  int idx = blockIdx.x * 256 + threadIdx.x;
  if (idx >= B2 * 64 * HW) return;
  int p = idx & (HW - 1);
  int bc = idx >> 12;
  int co = bc & 63, b = bc >> 6;
  const float* w = mp_w + co * 64;
  float a = mp_b[co];
#pragma unroll
  for (int h = 0; h < 4; ++h) {
    const float* ob = ot + ((size_t)(b * 4 + h) * HW + p) * 16;
#pragma unroll
    for (int d = 0; d < 16; ++d) a = fmaf(w[h * 16 + d], ob[d], a);
  }
  m0[idx] = a;
}

// ---------------- in_proj: xz = m0 @ in_w.T ; split xc / z ----------------
__global__ __launch_bounds__(256) void k_inproj(const float* __restrict__ m0,
                                                const float* __restrict__ in_w,
                                                float* __restrict__ xc, float* __restrict__ z) {
  __shared__ float lw[4 * 64];
  int jg = blockIdx.y & 63, b = blockIdx.y >> 6;
  int j0 = jg * 4;
  for (int i = threadIdx.x; i < 256; i += 256) lw[i] = in_w[j0 * 64 + i];
  __syncthreads();
  int p = blockIdx.x * 256 + threadIdx.x;
  const float* ib = m0 + (size_t)b * 64 * HW + p;
  float acc[4] = {0, 0, 0, 0};
#pragma unroll 8
  for (int ci = 0; ci < 64; ++ci) {
    float x = ib[ci * HW];
#pragma unroll
    for (int u = 0; u < 4; ++u) acc[u] = fmaf(lw[u * 64 + ci], x, acc[u]);
  }
#pragma unroll
  for (int u = 0; u < 4; ++u) {
    int j = j0 + u;
    if (j < 128) xc[(size_t)(b * 128 + j) * HW + p] = acc[u];
    else         z[(size_t)(b * 128 + j - 128) * HW + p] = acc[u];
  }
}

// ---------------- depthwise 3x3 conv (128 ch) + SiLU ----------------
__global__ void k_dw(const float* __restrict__ xc, const float* __restrict__ cv_w,
                     const float* __restrict__ cv_b, float* __restrict__ xc2) {
  int idx = blockIdx.x * 256 + threadIdx.x;
  if (idx >= B2 * 128 * HW) return;
  int p = idx & (HW - 1);
  int bc = idx >> 12;
  int c = bc & 127;
  int h = p >> 6, w = p & 63;
  const float* ib = xc + (size_t)bc * HW;
  const float* wt = cv_w + c * 9;
  float a = cv_b[c];
#pragma unroll
  for (int kh = -1; kh <= 1; ++kh) {
    int hh = h + kh;
    if (hh < 0 || hh > 63) continue;
#pragma unroll
    for (int kw = -1; kw <= 1; ++kw) {
      int ww = w + kw;
      if (ww < 0 || ww > 63) continue;
      a = fmaf(wt[(kh + 1) * 3 + (kw + 1)], ib[hh * 64 + ww], a);
    }
  }
  xc2[idx] = a / (1.f + __expf(-a));   // silu
}

// ---------------- spatial transpose copy ----------------
__global__ void k_tr(const float* __restrict__ xc2, float* __restrict__ xc2t) {
  int idx = blockIdx.x * 256 + threadIdx.x;
  if (idx >= B2 * 128 * HW) return;
  int l = idx & (HW - 1);
  size_t bd = (size_t)(idx >> 12);
  xc2t[idx] = xc2[(bd << 12) + ((l & 63) << 6) + (l >> 6)];
}

// ---------------- x_dbl projection, in scan order: proj[(bk,c,l)] ----------------
__global__ __launch_bounds__(256) void k_projs(const float* __restrict__ xc2,
                                               const float* __restrict__ xc2t,
                                               const float* __restrict__ xp_w,
                                               float* __restrict__ proj) {
  __shared__ float lw[6 * 128];
  int cg = blockIdx.y % 6;
  int bk = blockIdx.y / 6;
  int b = bk >> 2, k = bk & 3;
  int c0 = cg * 6;
  for (int i = threadIdx.x; i < 768; i += 256) lw[i] = xp_w[(k * 36 + c0) * 128 + i];
  __syncthreads();
  int l = blockIdx.x * 256 + threadIdx.x;
  const float* src = ((k & 1) ? xc2t : xc2) + (size_t)b * 128 * HW;
  int lx = (k >= 2) ? (4095 - l) : l;
  float acc[6] = {0, 0, 0, 0, 0, 0};
#pragma unroll 4
  for (int d = 0; d < 128; ++d) {
    float x = src[(size_t)d * HW + lx];
#pragma unroll
    for (int u = 0; u < 6; ++u) acc[u] = fmaf(lw[u * 128 + d], x, acc[u]);
  }
#pragma unroll
  for (int u = 0; u < 6; ++u)
    proj[(size_t)(bk * 36 + c0 + u) * L4 + l] = acc[u];
}

// ---------------- selective scan v4: cooperative dt precompute in LDS ----------------
template <int PC>
__global__ __launch_bounds__(256, 4) void k_scan2(const float* __restrict__ proj,
                                                  const float* __restrict__ xc2,
                                                  const float* __restrict__ xc2t,
                                                  const float* __restrict__ dtp_w,
                                                  const float* __restrict__ dtp_b,
                                                  const float* __restrict__ Alog,
                                                  const float* __restrict__ Dsk,
                                                  float* __restrict__ aprod,
                                                  float* __restrict__ hend,
                                                  const float* __restrict__ sstart,
                                                  float* __restrict__ ympre) {
  __shared__ float sxs[64][33];
  __shared__ float sdt[64][33];
  __shared__ float sB[16][36];
  __shared__ float sC[16][36];
  __shared__ float sdts[4][33];
  int tid = threadIdx.x;
  int nq = tid & 3;
  int dl = tid >> 2;               // 0..63
  int ch = blockIdx.x;             // chunk
  int dg = blockIdx.y;             // d-group (0/1)
  int bk = blockIdx.z;
  int b = bk >> 2, k = bk & 3;
  int d = dg * 64 + dl;
  int kd = k * 128 + d;
  float Ad[4];
  {
    float4 v = *(const float4*)(Alog + (size_t)kd * 16 + nq * 4);
    Ad[0] = -__expf(v.x); Ad[1] = -__expf(v.y); Ad[2] = -__expf(v.z); Ad[3] = -__expf(v.w);
  }
  float Dv = PC ? Dsk[kd] : 0.f;
  float h[4];
  if (PC) {
    float4 v = *(const float4*)(sstart + (size_t)ch * 16384 + ((size_t)bk * 128 + d) * 16 + nq * 4);
    h[0] = v.x; h[1] = v.y; h[2] = v.z; h[3] = v.w;
  } else {
    h[0] = h[1] = h[2] = h[3] = 0.f;
  }
  float ssum = 0.f;
  const float* pb = proj + (size_t)bk * 36 * L4;
  const float* srcb = ((k & 1) ? xc2t : xc2) + (size_t)b * 128 * HW;
  bool rev = (k >= 2);
  const int R = PC ? 36 : 20;

  for (int tile = 0; tile < 2; ++tile) {
    int lb = ch * 64 + tile * 32;
    __syncthreads();
    for (int i = tid; i < R * 32; i += 256) {
      int row = i >> 5, col = i & 31;
      float v = pb[(size_t)row * L4 + lb + col];
      if (row < 4) sdts[row][col] = v;
      else if (row < 20) sB[row - 4][col] = v;
      else sC[row - 20][col] = v;
    }
    for (int i = tid; i < 2048; i += 256) {
      int dd = i >> 5, t = i & 31;
      int l = lb + t;
      int lx = rev ? (4095 - l) : l;
      sxs[dd][t] = srcb[(size_t)(dg * 64 + dd) * HW + lx];
    }
    __syncthreads();
    // cooperative dt: 2048 entries, each computed exactly once
    for (int i = tid; i < 2048; i += 256) {
      int dd = i >> 5, t = i & 31;
      int kdd = k * 128 + dg * 64 + dd;
      float4 wv = *(const float4*)(dtp_w + (size_t)kdd * 4);
      float xr = fmaf(wv.x, sdts[0][t], fmaf(wv.y, sdts[1][t],
                 fmaf(wv.z, sdts[2][t], fmaf(wv.w, sdts[3][t], dtp_b[kdd]))));
      sdt[dd][t] = (xr > 20.f) ? xr : log1pf(__expf(xr));
    }
    __syncthreads();
    for (int tg = 0; tg < 32; tg += 4) {
      float spv[4], xsv[4], dxs[4];
#pragma unroll
      for (int j = 0; j < 4; ++j) {
        int t = tg + j;
        spv[j] = sdt[dl][t];
        xsv[j] = sxs[dl][t];
        dxs[j] = spv[j] * xsv[j];
        if (!PC) ssum += spv[j];
      }
      float y[4] = {0.f, 0.f, 0.f, 0.f};
#pragma unroll
      for (int i = 0; i < 4; ++i) {
        int n = nq * 4 + i;
        float hv = h[i], adn = Ad[i];
        float4 B4 = *(const float4*)&sB[n][tg];
        if (PC) {
          float4 C4 = *(const float4*)&sC[n][tg];
          hv = fmaf(__expf(spv[0] * adn), hv, dxs[0] * B4.x); y[0] = fmaf(hv, C4.x, y[0]);
          hv = fmaf(__expf(spv[1] * adn), hv, dxs[1] * B4.y); y[1] = fmaf(hv, C4.y, y[1]);
          hv = fmaf(__expf(spv[2] * adn), hv, dxs[2] * B4.z); y[2] = fmaf(hv, C4.z, y[2]);
          hv = fmaf(__expf(spv[3] * adn), hv, dxs[3] * B4.w); y[3] = fmaf(hv, C4.w, y[3]);
        } else {
          hv = fmaf(__expf(spv[0] * adn), hv, dxs[0] * B4.x);
          hv = fmaf(__expf(spv[1] * adn), hv, dxs[1] * B4.y);
          hv = fmaf(__expf(spv[2] * adn), hv, dxs[2] * B4.z);
          hv = fmaf(__expf(spv[3] * adn), hv, dxs[3] * B4.w);
        }
        h[i] = hv;
      }
      if (PC) {
#pragma unroll
        for (int j = 0; j < 4; ++j) {
          float yv = y[j];
          yv += __shfl_xor(yv, 1);
          yv += __shfl_xor(yv, 2);
          if (nq == 0) {
            int l = lb + tg + j;
            int pp;
            if (k == 0) pp = l;
            else if (k == 1) pp = ((l & 63) << 6) | (l >> 6);
            else if (k == 2) pp = 4095 - l;
            else { int lf = 4095 - l; pp = ((lf & 63) << 6) | (lf >> 6); }
            atomicAdd(ympre + ((size_t)b * HW + pp) * 128 + d, yv + Dv * xsv[j]);
          }
        }
      }
    }
  }
  if (!PC) {
    size_t base = (size_t)ch * 16384 + ((size_t)bk * 128 + d) * 16 + nq * 4;
#pragma unroll
    for (int i = 0; i < 4; ++i) {
      aprod[base + i] = __expf(Ad[i] * ssum);
      hend[base + i] = h[i];
    }
  }
}

// ---------------- phase B: combine chunk summaries (layout [ch][bk][d][n]) ----------------
__global__ void k_scanB(const float* __restrict__ aprod, const float* __restrict__ hend,
                        float* __restrict__ sstart) {
  int idx = blockIdx.x * 256 + threadIdx.x;
  if (idx >= 16384) return;
  float s = 0.f;
  for (int c = 0; c < NCH; ++c) {
    size_t o = (size_t)c * 16384 + idx;
    sstart[o] = s;
    s = fmaf(aprod[o], s, hend[o]);
  }
}

// ---------------- merge done via atomics; LN(128) + silu(z) gate (in-place ym->g) ----------------
__global__ __launch_bounds__(128) void k_merge(const float* __restrict__ ympre,
                                               const float* __restrict__ z,
                                               const float* __restrict__ on_g,
                                               const float* __restrict__ on_b,
                                               float* __restrict__ g) {
  int p = blockIdx.x & (HW - 1), b = blockIdx.x >> 12;
  int d = threadIdx.x;
  float v = ympre[((size_t)b * HW + p) * 128 + d];
  float s = v, sq = v * v;
#pragma unroll
  for (int off = 32; off; off >>= 1) { s += __shfl_xor(s, off); sq += __shfl_xor(sq, off); }
  __shared__ float sh[4];
  if ((threadIdx.x & 63) == 0) { sh[(threadIdx.x >> 6) * 2] = s; sh[(threadIdx.x >> 6) * 2 + 1] = sq; }
  __syncthreads();
  float S = sh[0] + sh[2], SQ = sh[1] + sh[3];
  float mu = S * (1.f / 128.f);
  float var = SQ * (1.f / 128.f) - mu * mu;
  float rs = rsqrtf(var + 1e-5f);
  float gn = (v - mu) * rs * on_g[d] + on_b[d];
  float zv = z[((size_t)(b * 128 + d)) * HW + p];
  float sil = zv / (1.f + __expf(-zv));
  g[((size_t)b * HW + p) * 128 + d] = gn * sil;
}

// ---------------- out proj + layerscale1 residual ----------------
__global__ __launch_bounds__(256) void k_outproj(const float* __restrict__ g,
                                                 const float* __restrict__ out_w,
                                                 const float* __restrict__ t,
                                                 const float* __restrict__ ls1_w,
                                                 const float* __restrict__ ls1_b,
                                                 float* __restrict__ t1) {
  __shared__ float lw[4 * 128];
  int cg = blockIdx.y & 15, b = blockIdx.y >> 4;
  int c0 = cg * 4;
  for (int i = threadIdx.x; i < 512; i += 256) lw[i] = out_w[c0 * 128 + i];
  __syncthreads();
  int p = blockIdx.x * 256 + threadIdx.x;
  const float* gr = g + ((size_t)b * HW + p) * 128;
  float acc[4] = {0, 0, 0, 0};
#pragma unroll 4
  for (int dd = 0; dd < 128; ++dd) {
    float x = gr[dd];
#pragma unroll
    for (int u = 0; u < 4; ++u) acc[u] = fmaf(lw[u * 128 + dd], x, acc[u]);
  }
#pragma unroll
  for (int u = 0; u < 4; ++u) {
    int co = c0 + u;
    size_t o = (size_t)(b * 64 + co) * HW + p;
    t1[o] = fmaf(t[o], ls1_w[co], ls1_b[co]) + acc[u];
  }
}

// ---------------- mlp f1 + exact gelu ----------------
__global__ __launch_bounds__(256) void k_f1(const float* __restrict__ xln2,
                                            const float* __restrict__ f1_w,
                                            const float* __restrict__ f1_b,
                                            float* __restrict__ u1) {
  __shared__ float lw[8 * 64];
  int cg = blockIdx.y & 31, b = blockIdx.y >> 5;
  int c0 = cg * 8;
  for (int i = threadIdx.x; i < 512; i += 256) lw[i] = f1_w[c0 * 64 + i];
  __syncthreads();
  int p = blockIdx.x * 256 + threadIdx.x;
  const float* ib = xln2 + (size_t)b * 64 * HW + p;
  float acc[8] = {0, 0, 0, 0, 0, 0, 0, 0};
#pragma unroll 8
  for (int ci = 0; ci < 64; ++ci) {
    float x = ib[ci * HW];
#pragma unroll
    for (int u = 0; u < 8; ++u) acc[u] = fmaf(lw[u * 64 + ci], x, acc[u]);
  }
#pragma unroll
  for (int u = 0; u < 8; ++u) {
    float v = acc[u] + f1_b[c0 + u];
    v = 0.5f * v * (1.f + erff(v * 0.70710678118654752440f));
    u1[(size_t)(b * 256 + c0 + u) * HW + p] = v;
  }
}

// ---------------- mlp f2 + layerscale2 residual + duplicated output ----------------
__global__ __launch_bounds__(256) void k_f2(const float* __restrict__ u1,
                                            const float* __restrict__ f2_w,
                                            const float* __restrict__ f2_b,
                                            const float* __restrict__ t1,
                                            const float* __restrict__ ls2_w,
                                            const float* __restrict__ ls2_b,
                                            float* __restrict__ out) {
  __shared__ float lw[4 * 256];
  int cg = blockIdx.y & 15, b = blockIdx.y >> 4;
  int c0 = cg * 4;
  for (int i = threadIdx.x; i < 1024; i += 256) lw[i] = f2_w[c0 * 256 + i];
  __syncthreads();
  int p = blockIdx.x * 256 + threadIdx.x;
  const float* ib = u1 + (size_t)b * 256 * HW + p;
  float acc[4] = {0, 0, 0, 0};
#pragma unroll 4
  for (int ci = 0; ci < 256; ++ci) {
    float x = ib[(size_t)ci * HW];
#pragma unroll
    for (int u = 0; u < 4; ++u) acc[u] = fmaf(lw[u * 256 + ci], x, acc[u]);
  }
#pragma unroll
  for (int u = 0; u < 4; ++u) {
    int co = c0 + u;
    size_t o = (size_t)(b * 64 + co) * HW + p;
    float v = fmaf(t1[o], ls2_w[co], ls2_b[co]) + acc[u] + f2_b[co];
    out[o] = v;
    out[o + (size_t)B2 * 64 * HW] = v;
  }
}

extern "C" void kernel_launch(void* const* d_in, const int* in_sizes, int n_in,
                              void* d_out, int out_size, void* d_ws, size_t ws_size,
                              hipStream_t stream) {
  const float* x     = (const float*)d_in[0];
  const float* res   = (const float*)d_in[1];
  const float* smf   = (const float*)d_in[2];
  const float* rc0_w = (const float*)d_in[3];
  const float* rcp_w = (const float*)d_in[4];
  const float* rcp_g = (const float*)d_in[5];
  const float* rcp_b = (const float*)d_in[6];
  const float* pe_w  = (const float*)d_in[7];
  const float* pe_b  = (const float*)d_in[8];
  const float* n1_g  = (const float*)d_in[9];
  const float* n1_b  = (const float*)d_in[10];
  const float* n2_g  = (const float*)d_in[11];
  const float* n2_b  = (const float*)d_in[12];
  const float* q_w   = (const float*)d_in[13];
  const float* q_b   = (const float*)d_in[14];
  const float* sr_w  = (const float*)d_in[15];
  const float* sr_b  = (const float*)d_in[16];
  const float* srn_g = (const float*)d_in[17];
  const float* srn_b = (const float*)d_in[18];
  const float* k_w   = (const float*)d_in[19];
  const float* k_b   = (const float*)d_in[20];
  const float* v_w   = (const float*)d_in[21];
  const float* v_b   = (const float*)d_in[22];
  const float* mp_w  = (const float*)d_in[23];
  const float* mp_b  = (const float*)d_in[24];
  const float* in_w  = (const float*)d_in[25];
  const float* cv_w  = (const float*)d_in[26];
  const float* cv_b  = (const float*)d_in[27];
  const float* xp_w  = (const float*)d_in[28];
  const float* dtp_w = (const float*)d_in[29];
  const float* dtp_b = (const float*)d_in[30];
  const float* Alog  = (const float*)d_in[31];
  const float* Dsk   = (const float*)d_in[32];
  const float* on_g  = (const float*)d_in[33];
  const float* on_b  = (const float*)d_in[34];
  const float* out_w = (const float*)d_in[35];
  const float* ls1_w = (const float*)d_in[36];
  const float* ls1_b = (const float*)d_in[37];
  const float* ls2_w = (const float*)d_in[38];
  const float* ls2_b = (const float*)d_in[39];
  const float* f1_w  = (const float*)d_in[40];
  const float* f1_b  = (const float*)d_in[41];
  const float* f2_w  = (const float*)d_in[42];
  const float* f2_b  = (const float*)d_in[43];
  float* ws = (float*)d_ws;
  float* out = (float*)d_out;

  hipMemsetAsync(ws + OFF_RSHUF, 0, (size_t)B2 * RS_B * sizeof(float), stream);
  k_rconv0<<<dim3(2112), dim3(256), 0, stream>>>(res, rc0_w, ws + OFF_RSHUF);
  k_rconv3<<<dim3(16, 44), dim3(256), 0, stream>>>(ws + OFF_RSHUF, rcp_w, rcp_g, rcp_b, ws + OFF_SHORT);
  k_up<<<dim3(4096), dim3(256), 0, stream>>>(smf, x, ws + OFF_SHORT, ws + OFF_INP);
  k_pe<<<dim3(2048), dim3(256), 0, stream>>>(ws + OFF_INP, pe_w, pe_b, ws + OFF_T);
  k_lnc64<<<dim3(128), dim3(256), 0, stream>>>(ws + OFF_T, n1_g, n1_b, ws + OFF_XLN);
  k_sr<<<dim3(4, 52), dim3(256), 0, stream>>>(ws + OFF_SHORT, sr_w, sr_b, ws + OFF_SRAW);
  k_ln130<<<dim3(2048), dim3(64), 0, stream>>>(ws + OFF_SRAW, srn_g, srn_b, ws + OFF_SRED);
  k_kv<<<dim3(1024), dim3(256), 0, stream>>>(ws + OFF_SRED, k_w, k_b, v_w, v_b, ws + OFF_KT, ws + OFF_VT);
  k_q<<<dim3(2048), dim3(256), 0, stream>>>(ws + OFF_XLN, q_w, q_b, ws + OFF_QT);
  k_attn1<<<dim3(8, 8, 8), dim3(256), 0, stream>>>(ws + OFF_QT, ws + OFF_KT, ws + OFF_VT, ws + OFF_PART);
  k_attn2<<<dim3(128), dim3(256), 0, stream>>>(ws + OFF_PART, ws + OFF_OT);
  k_mp<<<dim3(2048), dim3(256), 0, stream>>>(ws + OFF_OT, mp_w, mp_b, ws + OFF_M0);
  k_inproj<<<dim3(16, 128), dim3(256), 0, stream>>>(ws + OFF_M0, in_w, ws + OFF_XC, ws + OFF_Z);
  k_dw<<<dim3(4096), dim3(256), 0, stream>>>(ws + OFF_XC, cv_w, cv_b, ws + OFF_XC2);
  k_tr<<<dim3(4096), dim3(256), 0, stream>>>(ws + OFF_XC2, ws + OFF_XC2T);
  k_projs<<<dim3(16, 48), dim3(256), 0, stream>>>(ws + OFF_XC2, ws + OFF_XC2T, xp_w, ws + OFF_PROJ);
  k_scan2<0><<<dim3(64, 2, 8), dim3(256), 0, stream>>>(ws + OFF_PROJ, ws + OFF_XC2, ws + OFF_XC2T,
      dtp_w, dtp_b, Alog, Dsk, ws + OFF_APROD, ws + OFF_HEND, ws + OFF_SSTART, ws + OFF_YM);
  k_scanB<<<dim3(64), dim3(256), 0, stream>>>(ws + OFF_APROD, ws + OFF_HEND, ws + OFF_SSTART);
  hipMemsetAsync(ws + OFF_YM, 0, (size_t)B2 * HW * 128 * sizeof(float), stream);
  k_scan2<1><<<dim3(64, 2, 8), dim3(256), 0, stream>>>(ws + OFF_PROJ, ws + OFF_XC2, ws + OFF_XC2T,
      dtp_w, dtp_b, Alog, Dsk, ws + OFF_APROD, ws + OFF_HEND, ws + OFF_SSTART, ws + OFF_YM);
  k_merge<<<dim3(8192), dim3(128), 0, stream>>>(ws + OFF_YM, ws + OFF_Z, on_g, on_b, ws + OFF_YM);
  k_outproj<<<dim3(16, 32), dim3(256), 0, stream>>>(ws + OFF_YM, out_w, ws + OFF_T, ls1_w, ls1_b, ws + OFF_T1);
  k_lnc64<<<dim3(128), dim3(256), 0, stream>>>(ws + OFF_T1, n2_g, n2_b, ws + OFF_XLN);
  k_f1<<<dim3(16, 64), dim3(256), 0, stream>>>(ws + OFF_XLN, f1_w, f1_b, ws + OFF_U1);
  k_f2<<<dim3(16, 32), dim3(256), 0, stream>>>(ws + OFF_U1, f2_w, f2_b, ws + OFF_T1, ls2_w, ls2_b, out);
}

// Round 14
// 497.984 us; speedup vs baseline: 1.0210x; 1.0210x over previous
//
#include <hip/hip_runtime.h>
#include <math.h>

#define B2 2
#define HW 4096
#define L4 4096
#define NCH 64          // chunks for the scan (CLEN = 64)

// ---------------- workspace offsets (floats) ----------------
enum : size_t {
  OFF_APROD  = 0,         // 16384*64 = 1048576, lives only during scan (region dead then)
  OFF_HEND   = 1048576,   // 1048576
  OFF_SSTART = 2097152,   // 1048576, ends 3145728
  OFF_INP    = 0,
  OFF_SHORT  = 524288,
  OFF_RSHUF  = 7118848,   // padded [B][66][66][66]; overlays XC2 region (dead during res branch)
  OFF_XLN    = 2129920,   // reused as xln2 later
  OFF_SRAW   = 2654208,
  OFF_SRED   = 2920448,
  OFF_QT     = 3186688,
  OFF_KT     = 3710976,
  OFF_VT     = 3842048,
  OFF_OT     = 3973120,
  OFF_M0     = 4497408,
  OFF_XC     = 3186688,   // overlays qt/kt/vt/ot (dead by then)
  OFF_U1     = 0,         // overlays inp + scan summaries (dead by then)
  OFF_T      = 5021696,
  OFF_T1     = 5545984,
  OFF_Z      = 6070272,
  OFF_XC2    = 7118848,
  OFF_XC2T   = 8167424,
  OFF_PROJ   = 9216000,
  OFF_YM     = 11182080,  // ym accumulator, then g (in-place)
  OFF_PART   = 7118848,   // attention partials (8 ktiles x 18), overlays xc2/xc2t/proj/ym head (dead during attn)
};

#define RS_CH 4356   // 66*66 padded spatial
#define RS_B  287496 // 66*4356

// ---------------- res branch: 1x1 conv + mean/max + channel shuffle -> PADDED rshuf ----------------
__global__ void k_rconv0(const float* __restrict__ res, const float* __restrict__ rc0_w,
                         float* __restrict__ rshufP) {
  int idx = blockIdx.x * 256 + threadIdx.x;
  if (idx >= B2 * 66 * HW) return;
  int p = idx & (HW - 1);
  int bc = idx >> 12;
  int c = bc % 66, b = bc / 66;
  int cc = (c % 22) * 3 + (c / 22);     // inverse of channel shuffle
  const float* rb = res + (size_t)b * 32 * HW + p;
  float v;
  if (cc < 64) {
    const float* w = rc0_w + cc * 32;
    float a = 0.f;
#pragma unroll
    for (int ic = 0; ic < 32; ++ic) a = fmaf(w[ic], rb[ic * HW], a);
    v = a;
  } else if (cc == 64) {
    float s = 0.f;
#pragma unroll
    for (int ic = 0; ic < 32; ++ic) s += rb[ic * HW];
    v = s * (1.f / 32.f);
  } else {
    float m = rb[0];
#pragma unroll
    for (int ic = 1; ic < 32; ++ic) m = fmaxf(m, rb[ic * HW]);
    v = m;
  }
  int h = p >> 6, w = p & 63;
  rshufP[(size_t)(b * 66 + c) * RS_CH + (h + 1) * 66 + (w + 1)] = v;
}

// ---------------- 3x3 conv 66->66 + BN + relu6 -> shortcut[0:66] ----------------
__global__ __launch_bounds__(256) void k_rconv3(const float* __restrict__ rshufP,
                                                const float* __restrict__ rcp_w,
                                                const float* __restrict__ rcp_g,
                                                const float* __restrict__ rcp_b,
                                                float* __restrict__ shortcut) {
  __shared__ float lw[3 * 594];
  int cg = blockIdx.y % 22, b = blockIdx.y / 22;
  int c0 = cg * 3;
  for (int i = threadIdx.x; i < 3 * 594; i += 256) lw[i] = rcp_w[c0 * 594 + i];
  __syncthreads();
  int p = blockIdx.x * 256 + threadIdx.x;
  int h = p >> 6, w = p & 63;
  const float* base = rshufP + (size_t)b * RS_B + h * 66 + w;
  float a0 = 0.f, a1 = 0.f, a2 = 0.f;
#pragma unroll 2
  for (int ci = 0; ci < 66; ++ci) {
    const float* ib = base + (size_t)ci * RS_CH;
    float x0 = ib[0],   x1 = ib[1],   x2 = ib[2];
    float x3 = ib[66],  x4 = ib[67],  x5 = ib[68];
    float x6 = ib[132], x7 = ib[133], x8 = ib[134];
    const float* q0 = lw + ci * 9;
    const float* q1 = lw + 594 + ci * 9;
    const float* q2 = lw + 1188 + ci * 9;
    a0 = fmaf(q0[0], x0, fmaf(q0[1], x1, fmaf(q0[2], x2, fmaf(q0[3], x3, fmaf(q0[4], x4,
         fmaf(q0[5], x5, fmaf(q0[6], x6, fmaf(q0[7], x7, fmaf(q0[8], x8, a0)))))))));
    a1 = fmaf(q1[0], x0, fmaf(q1[1], x1, fmaf(q1[2], x2, fmaf(q1[3], x3, fmaf(q1[4], x4,
         fmaf(q1[5], x5, fmaf(q1[6], x6, fmaf(q1[7], x7, fmaf(q1[8], x8, a1)))))))));
    a2 = fmaf(q2[0], x0, fmaf(q2[1], x1, fmaf(q2[2], x2, fmaf(q2[3], x3, fmaf(q2[4], x4,
         fmaf(q2[5], x5, fmaf(q2[6], x6, fmaf(q2[7], x7, fmaf(q2[8], x8, a2)))))))));
  }
  const float bscale = rsqrtf(1.f + 1e-5f);
  float acc[3] = {a0, a1, a2};
#pragma unroll
  for (int u = 0; u < 3; ++u) {
    int co = c0 + u;
    float v = acc[u] * (rcp_g[co] * bscale) + rcp_b[co];
    v = fminf(fmaxf(v, 0.f), 6.f);
    shortcut[(size_t)(b * 130 + co) * HW + p] = v;
  }
}

// ---------------- bilinear 2x upsample: smf -> shortcut[66:130], x -> inp ----------------
__global__ void k_up(const float* __restrict__ smf, const float* __restrict__ x,
                     float* __restrict__ shortcut, float* __restrict__ inp) {
  int idx = blockIdx.x * 256 + threadIdx.x;
  if (idx >= B2 * 128 * HW) return;
  int p = idx & (HW - 1);
  int bc = idx >> 12;
  int c = bc & 127, b = bc >> 7;
  int oh = p >> 6, ow = p & 63;
  int hp = oh >> 1, wp = ow >> 1;
  int ih0, ih1, iw0, iw1;
  float wh0, ww0;
  if (oh & 1) { ih0 = hp; ih1 = (hp + 1 > 31) ? 31 : hp + 1; wh0 = 0.75f; }
  else        { ih0 = (hp - 1 < 0) ? 0 : hp - 1; ih1 = hp; wh0 = 0.25f; }
  if (ow & 1) { iw0 = wp; iw1 = (wp + 1 > 31) ? 31 : wp + 1; ww0 = 0.75f; }
  else        { iw0 = (wp - 1 < 0) ? 0 : wp - 1; iw1 = wp; ww0 = 0.25f; }
  const float* src = (c < 64) ? (smf + (size_t)(b * 64 + c) * 1024)
                              : (x + (size_t)(b * 64 + (c - 64)) * 1024);
  float v00 = src[ih0 * 32 + iw0], v01 = src[ih0 * 32 + iw1];
  float v10 = src[ih1 * 32 + iw0], v11 = src[ih1 * 32 + iw1];
  float v = wh0 * (ww0 * v00 + (1.f - ww0) * v01) + (1.f - wh0) * (ww0 * v10 + (1.f - ww0) * v11);
  if (c < 64) shortcut[(size_t)(b * 130 + 66 + c) * HW + p] = v;
  else        inp[(size_t)(b * 64 + (c - 64)) * HW + p] = v;
}

// ---------------- t = inp + dwconv3x3(inp) + pe_b ----------------
__global__ void k_pe(const float* __restrict__ inp, const float* __restrict__ pe_w,
                     const float* __restrict__ pe_b, float* __restrict__ t) {
  int idx = blockIdx.x * 256 + threadIdx.x;
  if (idx >= B2 * 64 * HW) return;
  int p = idx & (HW - 1);
  int bc = idx >> 12;
  int c = bc & 63;
  int h = p >> 6, w = p & 63;
  const float* ib = inp + (size_t)bc * HW;
  const float* wt = pe_w + c * 9;
  float a = pe_b[c];
#pragma unroll
  for (int kh = -1; kh <= 1; ++kh) {
    int hh = h + kh;
    if (hh < 0 || hh > 63) continue;
#pragma unroll
    for (int kw = -1; kw <= 1; ++kw) {
      int ww = w + kw;
      if (ww < 0 || ww > 63) continue;
      a = fmaf(wt[(kh + 1) * 3 + (kw + 1)], ib[hh * 64 + ww], a);
    }
  }
  t[idx] = ib[p] + a;
}

// ---------------- LayerNorm over 64 channels (NCHW), widened: 128 blocks ----------------
__global__ __launch_bounds__(256) void k_lnc64(const float* __restrict__ in,
                                               const float* __restrict__ g,
                                               const float* __restrict__ bb,
                                               float* __restrict__ out) {
  __shared__ float sred[2][4][64];
  int tid = threadIdx.x;
  int pos = tid & 63, cq = tid >> 6;        // 4 channel-quarters
  int gp = blockIdx.x * 64 + pos;           // global position
  int p = gp & (HW - 1), b = gp >> 12;
  const float* ib = in + (size_t)b * 64 * HW + p;
  float s = 0.f, sq = 0.f;
#pragma unroll
  for (int i = 0; i < 16; ++i) {
    float v = ib[(cq * 16 + i) * HW];
    s += v; sq = fmaf(v, v, sq);
  }
  sred[0][cq][pos] = s;
  sred[1][cq][pos] = sq;
  __syncthreads();
  float S  = sred[0][0][pos] + sred[0][1][pos] + sred[0][2][pos] + sred[0][3][pos];
  float SQ = sred[1][0][pos] + sred[1][1][pos] + sred[1][2][pos] + sred[1][3][pos];
  float mu = S * (1.f / 64.f);
  float var = SQ * (1.f / 64.f) - mu * mu;
  float rs = rsqrtf(var + 1e-5f);
  float* ob = out + (size_t)b * 64 * HW + p;
#pragma unroll
  for (int i = 0; i < 16; ++i) {
    int c = cq * 16 + i;
    ob[c * HW] = (ib[c * HW] - mu) * rs * g[c] + bb[c];
  }
}

// ---------------- 2x2 stride-2 conv 130->130 + bias ----------------
__global__ __launch_bounds__(256) void k_sr(const float* __restrict__ shortcut,
                                            const float* __restrict__ sr_w,
                                            const float* __restrict__ sr_b,
                                            float* __restrict__ sraw) {
  __shared__ float lw[5 * 520];
  int cg = blockIdx.y % 26, b = blockIdx.y / 26;
  int c0 = cg * 5;
  for (int i = threadIdx.x; i < 5 * 520; i += 256) lw[i] = sr_w[c0 * 520 + i];
  __syncthreads();
  int op = blockIdx.x * 256 + threadIdx.x;
  int oh = op >> 5, ow = op & 31;
  const float* ib = shortcut + (size_t)b * 130 * HW + (oh * 2) * 64 + ow * 2;
  float acc[5] = {0, 0, 0, 0, 0};
  for (int ci = 0; ci < 130; ++ci) {
    const float* q = ib + (size_t)ci * HW;
    float x00 = q[0], x01 = q[1], x10 = q[64], x11 = q[65];
#pragma unroll
    for (int u = 0; u < 5; ++u) {
      const float* wp = lw + u * 520 + ci * 4;
      acc[u] = fmaf(wp[0], x00, fmaf(wp[1], x01, fmaf(wp[2], x10, fmaf(wp[3], x11, acc[u]))));
    }
  }
#pragma unroll
  for (int u = 0; u < 5; ++u)
    sraw[(size_t)(b * 130 + c0 + u) * 1024 + op] = acc[u] + sr_b[c0 + u];
}

// ---------------- LayerNorm over 130 channels ----------------
__global__ __launch_bounds__(64) void k_ln130(const float* __restrict__ sraw,
                                              const float* __restrict__ g,
                                              const float* __restrict__ bb,
                                              float* __restrict__ sred) {
  int op = blockIdx.x & 1023, b = blockIdx.x >> 10;
  int t = threadIdx.x;
  const float* ib = sraw + (size_t)b * 130 * 1024 + op;
  float s = 0.f, sq = 0.f;
  for (int c = t; c < 130; c += 64) { float v = ib[c * 1024]; s += v; sq = fmaf(v, v, sq); }
#pragma unroll
  for (int off = 32; off; off >>= 1) { s += __shfl_xor(s, off); sq += __shfl_xor(sq, off); }
  float mu = s * (1.f / 130.f);
  float var = sq * (1.f / 130.f) - mu * mu;
  float rs = rsqrtf(var + 1e-5f);
  float* ob = sred + (size_t)b * 130 * 1024 + op;
  for (int c = t; c < 130; c += 64) ob[c * 1024] = (ib[c * 1024] - mu) * rs * g[c] + bb[c];
}

// ---------------- k/v 1x1 convs (130 -> 64 each), layout (b,h,key,16) ----------------
__global__ void k_kv(const float* __restrict__ sred, const float* __restrict__ k_w,
                     const float* __restrict__ k_b, const float* __restrict__ v_w,
                     const float* __restrict__ v_b, float* __restrict__ kt, float* __restrict__ vt) {
  int idx = blockIdx.x * 256 + threadIdx.x;
  if (idx >= B2 * 128 * 1024) return;
  int op = idx & 1023;
  int bc = idx >> 10;
  int c = bc & 127, b = bc >> 7;
  bool isv = c >= 64;
  int co = c & 63;
  const float* w = (isv ? v_w : k_w) + co * 130;
  const float* ib = sred + (size_t)b * 130 * 1024 + op;
  float a = (isv ? v_b : k_b)[co];
  for (int ci = 0; ci < 130; ++ci) a = fmaf(w[ci], ib[ci * 1024], a);
  float* dst = isv ? vt : kt;
  dst[((size_t)(b * 4 + (co >> 4)) * 1024 + op) * 16 + (co & 15)] = a;
}

// ---------------- q 1x1 conv, layout (b,h,p,16) ----------------
__global__ void k_q(const float* __restrict__ xln, const float* __restrict__ q_w,
                    const float* __restrict__ q_b, float* __restrict__ qt) {
  int idx = blockIdx.x * 256 + threadIdx.x;
  if (idx >= B2 * 64 * HW) return;
  int p = idx & (HW - 1);
  int bc = idx >> 12;
  int co = bc & 63, b = bc >> 6;
  const float* ib = xln + (size_t)b * 64 * HW + p;
  const float* w = q_w + co * 64;
  float a = q_b[co];
#pragma unroll
  for (int ci = 0; ci < 64; ++ci) a = fmaf(w[ci], ib[ci * HW], a);
  qt[((size_t)(b * 4 + (co >> 4)) * HW + p) * 16 + (co & 15)] = a;
}

// ---------------- flash attention phase 1 v4: 1 query/thread, ktile=128, 1024 blocks ----------------
// grid (8 ktile, 16 qtile, 8 bh) = 1024 blocks -> 4 waves/SIMD for latency hiding.
__global__ __launch_bounds__(256) void k_attn1(const float* __restrict__ qt,
                                               const float* __restrict__ kt,
                                               const float* __restrict__ vt,
                                               float* __restrict__ part) {
  __shared__ float sk[128 * 16];
  __shared__ float sv[128 * 16];
  int ktile = blockIdx.x, qtile = blockIdx.y, bh = blockIdx.z;
  int tid = threadIdx.x;
  const float* kb = kt + ((size_t)bh * 1024 + ktile * 128) * 16;
  const float* vb = vt + ((size_t)bh * 1024 + ktile * 128) * 16;
  for (int i = tid * 4; i < 2048; i += 1024) {
    *(float4*)&sk[i] = *(const float4*)&kb[i];
    *(float4*)&sv[i] = *(const float4*)&vb[i];
  }
  __syncthreads();
  int q = qtile * 256 + tid;
  const float sc = 0.25f;
  const float4* qr = (const float4*)(qt + ((size_t)bh * HW + q) * 16);
  float4 a0 = qr[0], a1 = qr[1], a2 = qr[2], a3 = qr[3];
  a0.x *= sc; a0.y *= sc; a0.z *= sc; a0.w *= sc;
  a1.x *= sc; a1.y *= sc; a1.z *= sc; a1.w *= sc;
  a2.x *= sc; a2.y *= sc; a2.z *= sc; a2.w *= sc;
  a3.x *= sc; a3.y *= sc; a3.z *= sc; a3.w *= sc;
  float m = -1e30f, l = 0.f;
  float acc[16];
#pragma unroll
  for (int i = 0; i < 16; ++i) acc[i] = 0.f;
  for (int kk = 0; kk < 128; ++kk) {
    const float4* kr = (const float4*)&sk[kk * 16];
    float4 k0 = kr[0], k1 = kr[1], k2 = kr[2], k3 = kr[3];
    // 4 independent partials
    float s0 = fmaf(a0.x, k0.x, fmaf(a0.y, k0.y, fmaf(a0.z, k0.z, a0.w * k0.w)));
    float s1 = fmaf(a1.x, k1.x, fmaf(a1.y, k1.y, fmaf(a1.z, k1.z, a1.w * k1.w)));
    float s2 = fmaf(a2.x, k2.x, fmaf(a2.y, k2.y, fmaf(a2.z, k2.z, a2.w * k2.w)));
    float s3 = fmaf(a3.x, k3.x, fmaf(a3.y, k3.y, fmaf(a3.z, k3.z, a3.w * k3.w)));
    float s = (s0 + s1) + (s2 + s3);
    if (s > m) {
      float r = __expf(m - s);
      l *= r;
#pragma unroll
      for (int i = 0; i < 16; ++i) acc[i] *= r;
      m = s;
    }
    float pe = __expf(s - m);
    l += pe;
    const float4* vr = (const float4*)&sv[kk * 16];
    float4 v0 = vr[0], v1 = vr[1], v2 = vr[2], v3 = vr[3];
    acc[0] = fmaf(pe, v0.x, acc[0]);  acc[1] = fmaf(pe, v0.y, acc[1]);
    acc[2] = fmaf(pe, v0.z, acc[2]);  acc[3] = fmaf(pe, v0.w, acc[3]);
    acc[4] = fmaf(pe, v1.x, acc[4]);  acc[5] = fmaf(pe, v1.y, acc[5]);
    acc[6] = fmaf(pe, v1.z, acc[6]);  acc[7] = fmaf(pe, v1.w, acc[7]);
    acc[8] = fmaf(pe, v2.x, acc[8]);  acc[9] = fmaf(pe, v2.y, acc[9]);
    acc[10] = fmaf(pe, v2.z, acc[10]); acc[11] = fmaf(pe, v2.w, acc[11]);
    acc[12] = fmaf(pe, v3.x, acc[12]); acc[13] = fmaf(pe, v3.y, acc[13]);
    acc[14] = fmaf(pe, v3.z, acc[14]); acc[15] = fmaf(pe, v3.w, acc[15]);
  }
  float* o = part + (((size_t)bh * 8 + ktile) * HW + q) * 18;
#pragma unroll
  for (int i = 0; i < 16; ++i) o[i] = acc[i];
  o[16] = m;
  o[17] = l;
}

// ---------------- flash attention phase 2: merge 8 ktile partials ----------------
__global__ void k_attn2(const float* __restrict__ part, float* __restrict__ ot) {
  int idx = blockIdx.x * 256 + threadIdx.x;
  if (idx >= B2 * 4 * HW) return;
  int q = idx & (HW - 1), bh = idx >> 12;
  float M = -1e30f;
#pragma unroll
  for (int kt8 = 0; kt8 < 8; ++kt8)
    M = fmaxf(M, part[(((size_t)bh * 8 + kt8) * HW + q) * 18 + 16]);
  float L = 0.f;
  float o[16];
#pragma unroll
  for (int i = 0; i < 16; ++i) o[i] = 0.f;
#pragma unroll
  for (int kt8 = 0; kt8 < 8; ++kt8) {
    const float* p = part + (((size_t)bh * 8 + kt8) * HW + q) * 18;
    float w = __expf(p[16] - M);
    L = fmaf(p[17], w, L);
#pragma unroll
    for (int i = 0; i < 16; ++i) o[i] = fmaf(p[i], w, o[i]);
  }
  float inv = 1.f / L;
  float* ob = ot + ((size_t)bh * HW + q) * 16;
#pragma unroll
  for (int i = 0; i < 16; ++i) ob[i] = o[i] * inv;
}

// ---------------- mp 1x1 conv -> m0 (NCHW) ----------------
__global__ void k_mp(const float* __restrict__ ot, const float* __restrict__ mp_w,
                     const float* __restrict__ mp_b, float* __restrict__ m0) {
  int idx = blockIdx.x * 256 + threadIdx.x;
  if (idx >= B2 * 64 * HW) return;
  int p = idx & (HW - 1);
  int bc = idx >> 12;
  int co = bc & 63, b = bc >> 6;
  const float* w = mp_w + co * 64;
  float a = mp_b[co];
#pragma unroll
  for (int h = 0; h < 4; ++h) {
    const float* ob = ot + ((size_t)(b * 4 + h) * HW + p) * 16;
#pragma unroll
    for (int d = 0; d < 16; ++d) a = fmaf(w[h * 16 + d], ob[d], a);
  }
  m0[idx] = a;
}

// ---------------- in_proj: xz = m0 @ in_w.T ; split xc / z ----------------
__global__ __launch_bounds__(256) void k_inproj(const float* __restrict__ m0,
                                                const float* __restrict__ in_w,
                                                float* __restrict__ xc, float* __restrict__ z) {
  __shared__ float lw[4 * 64];
  int jg = blockIdx.y & 63, b = blockIdx.y >> 6;
  int j0 = jg * 4;
  for (int i = threadIdx.x; i < 256; i += 256) lw[i] = in_w[j0 * 64 + i];
  __syncthreads();
  int p = blockIdx.x * 256 + threadIdx.x;
  const float* ib = m0 + (size_t)b * 64 * HW + p;
  float acc[4] = {0, 0, 0, 0};
#pragma unroll 8
  for (int ci = 0; ci < 64; ++ci) {
    float x = ib[ci * HW];
#pragma unroll
    for (int u = 0; u < 4; ++u) acc[u] = fmaf(lw[u * 64 + ci], x, acc[u]);
  }
#pragma unroll
  for (int u = 0; u < 4; ++u) {
    int j = j0 + u;
    if (j < 128) xc[(size_t)(b * 128 + j) * HW + p] = acc[u];
    else         z[(size_t)(b * 128 + j - 128) * HW + p] = acc[u];
  }
}

// ---------------- depthwise 3x3 conv (128 ch) + SiLU ----------------
__global__ void k_dw(const float* __restrict__ xc, const float* __restrict__ cv_w,
                     const float* __restrict__ cv_b, float* __restrict__ xc2) {
  int idx = blockIdx.x * 256 + threadIdx.x;
  if (idx >= B2 * 128 * HW) return;
  int p = idx & (HW - 1);
  int bc = idx >> 12;
  int c = bc & 127;
  int h = p >> 6, w = p & 63;
  const float* ib = xc + (size_t)bc * HW;
  const float* wt = cv_w + c * 9;
  float a = cv_b[c];
#pragma unroll
  for (int kh = -1; kh <= 1; ++kh) {
    int hh = h + kh;
    if (hh < 0 || hh > 63) continue;
#pragma unroll
    for (int kw = -1; kw <= 1; ++kw) {
      int ww = w + kw;
      if (ww < 0 || ww > 63) continue;
      a = fmaf(wt[(kh + 1) * 3 + (kw + 1)], ib[hh * 64 + ww], a);
    }
  }
  xc2[idx] = a / (1.f + __expf(-a));   // silu
}

// ---------------- spatial transpose copy ----------------
__global__ void k_tr(const float* __restrict__ xc2, float* __restrict__ xc2t) {
  int idx = blockIdx.x * 256 + threadIdx.x;
  if (idx >= B2 * 128 * HW) return;
  int l = idx & (HW - 1);
  size_t bd = (size_t)(idx >> 12);
  xc2t[idx] = xc2[(bd << 12) + ((l & 63) << 6) + (l >> 6)];
}

// ---------------- x_dbl projection, in scan order: proj[(bk,c,l)] ----------------
__global__ __launch_bounds__(256) void k_projs(const float* __restrict__ xc2,
                                               const float* __restrict__ xc2t,
                                               const float* __restrict__ xp_w,
                                               float* __restrict__ proj) {
  __shared__ float lw[6 * 128];
  int cg = blockIdx.y % 6;
  int bk = blockIdx.y / 6;
  int b = bk >> 2, k = bk & 3;
  int c0 = cg * 6;
  for (int i = threadIdx.x; i < 768; i += 256) lw[i] = xp_w[(k * 36 + c0) * 128 + i];
  __syncthreads();
  int l = blockIdx.x * 256 + threadIdx.x;
  const float* src = ((k & 1) ? xc2t : xc2) + (size_t)b * 128 * HW;
  int lx = (k >= 2) ? (4095 - l) : l;
  float acc[6] = {0, 0, 0, 0, 0, 0};
#pragma unroll 4
  for (int d = 0; d < 128; ++d) {
    float x = src[(size_t)d * HW + lx];
#pragma unroll
    for (int u = 0; u < 6; ++u) acc[u] = fmaf(lw[u * 128 + d], x, acc[u]);
  }
#pragma unroll
  for (int u = 0; u < 6; ++u)
    proj[(size_t)(bk * 36 + c0 + u) * L4 + l] = acc[u];
}

// ---------------- selective scan v4: cooperative dt precompute in LDS ----------------
template <int PC>
__global__ __launch_bounds__(256, 4) void k_scan2(const float* __restrict__ proj,
                                                  const float* __restrict__ xc2,
                                                  const float* __restrict__ xc2t,
                                                  const float* __restrict__ dtp_w,
                                                  const float* __restrict__ dtp_b,
                                                  const float* __restrict__ Alog,
                                                  const float* __restrict__ Dsk,
                                                  float* __restrict__ aprod,
                                                  float* __restrict__ hend,
                                                  const float* __restrict__ sstart,
                                                  float* __restrict__ ympre) {
  __shared__ float sxs[64][33];
  __shared__ float sdt[64][33];
  __shared__ float sB[16][36];
  __shared__ float sC[16][36];
  __shared__ float sdts[4][33];
  int tid = threadIdx.x;
  int nq = tid & 3;
  int dl = tid >> 2;               // 0..63
  int ch = blockIdx.x;             // chunk
  int dg = blockIdx.y;             // d-group (0/1)
  int bk = blockIdx.z;
  int b = bk >> 2, k = bk & 3;
  int d = dg * 64 + dl;
  int kd = k * 128 + d;
  float Ad[4];
  {
    float4 v = *(const float4*)(Alog + (size_t)kd * 16 + nq * 4);
    Ad[0] = -__expf(v.x); Ad[1] = -__expf(v.y); Ad[2] = -__expf(v.z); Ad[3] = -__expf(v.w);
  }
  float Dv = PC ? Dsk[kd] : 0.f;
  float h[4];
  if (PC) {
    float4 v = *(const float4*)(sstart + (size_t)ch * 16384 + ((size_t)bk * 128 + d) * 16 + nq * 4);
    h[0] = v.x; h[1] = v.y; h[2] = v.z; h[3] = v.w;
  } else {
    h[0] = h[1] = h[2] = h[3] = 0.f;
  }
  float ssum = 0.f;
  const float* pb = proj + (size_t)bk * 36 * L4;
  const float* srcb = ((k & 1) ? xc2t : xc2) + (size_t)b * 128 * HW;
  bool rev = (k >= 2);
  const int R = PC ? 36 : 20;

  for (int tile = 0; tile < 2; ++tile) {
    int lb = ch * 64 + tile * 32;
    __syncthreads();
    for (int i = tid; i < R * 32; i += 256) {
      int row = i >> 5, col = i & 31;
      float v = pb[(size_t)row * L4 + lb + col];
      if (row < 4) sdts[row][col] = v;
      else if (row < 20) sB[row - 4][col] = v;
      else sC[row - 20][col] = v;
    }
    for (int i = tid; i < 2048; i += 256) {
      int dd = i >> 5, t = i & 31;
      int l = lb + t;
      int lx = rev ? (4095 - l) : l;
      sxs[dd][t] = srcb[(size_t)(dg * 64 + dd) * HW + lx];
    }
    __syncthreads();
    // cooperative dt: 2048 entries, each computed exactly once
    for (int i = tid; i < 2048; i += 256) {
      int dd = i >> 5, t = i & 31;
      int kdd = k * 128 + dg * 64 + dd;
      float4 wv = *(const float4*)(dtp_w + (size_t)kdd * 4);
      float xr = fmaf(wv.x, sdts[0][t], fmaf(wv.y, sdts[1][t],
                 fmaf(wv.z, sdts[2][t], fmaf(wv.w, sdts[3][t], dtp_b[kdd]))));
      sdt[dd][t] = (xr > 20.f) ? xr : log1pf(__expf(xr));
    }
    __syncthreads();
    for (int tg = 0; tg < 32; tg += 4) {
      float spv[4], xsv[4], dxs[4];
#pragma unroll
      for (int j = 0; j < 4; ++j) {
        int t = tg + j;
        spv[j] = sdt[dl][t];
        xsv[j] = sxs[dl][t];
        dxs[j] = spv[j] * xsv[j];
        if (!PC) ssum += spv[j];
      }
      float y[4] = {0.f, 0.f, 0.f, 0.f};
#pragma unroll
      for (int i = 0; i < 4; ++i) {
        int n = nq * 4 + i;
        float hv = h[i], adn = Ad[i];
        float4 B4 = *(const float4*)&sB[n][tg];
        if (PC) {
          float4 C4 = *(const float4*)&sC[n][tg];
          hv = fmaf(__expf(spv[0] * adn), hv, dxs[0] * B4.x); y[0] = fmaf(hv, C4.x, y[0]);
          hv = fmaf(__expf(spv[1] * adn), hv, dxs[1] * B4.y); y[1] = fmaf(hv, C4.y, y[1]);
          hv = fmaf(__expf(spv[2] * adn), hv, dxs[2] * B4.z); y[2] = fmaf(hv, C4.z, y[2]);
          hv = fmaf(__expf(spv[3] * adn), hv, dxs[3] * B4.w); y[3] = fmaf(hv, C4.w, y[3]);
        } else {
          hv = fmaf(__expf(spv[0] * adn), hv, dxs[0] * B4.x);
          hv = fmaf(__expf(spv[1] * adn), hv, dxs[1] * B4.y);
          hv = fmaf(__expf(spv[2] * adn), hv, dxs[2] * B4.z);
          hv = fmaf(__expf(spv[3] * adn), hv, dxs[3] * B4.w);
        }
        h[i] = hv;
      }
      if (PC) {
#pragma unroll
        for (int j = 0; j < 4; ++j) {
          float yv = y[j];
          yv += __shfl_xor(yv, 1);
          yv += __shfl_xor(yv, 2);
          if (nq == 0) {
            int l = lb + tg + j;
            int pp;
            if (k == 0) pp = l;
            else if (k == 1) pp = ((l & 63) << 6) | (l >> 6);
            else if (k == 2) pp = 4095 - l;
            else { int lf = 4095 - l; pp = ((lf & 63) << 6) | (lf >> 6); }
            atomicAdd(ympre + ((size_t)b * HW + pp) * 128 + d, yv + Dv * xsv[j]);
          }
        }
      }
    }
  }
  if (!PC) {
    size_t base = (size_t)ch * 16384 + ((size_t)bk * 128 + d) * 16 + nq * 4;
#pragma unroll
    for (int i = 0; i < 4; ++i) {
      aprod[base + i] = __expf(Ad[i] * ssum);
      hend[base + i] = h[i];
    }
  }
}

// ---------------- phase B: combine chunk summaries (layout [ch][bk][d][n]) ----------------
__global__ void k_scanB(const float* __restrict__ aprod, const float* __restrict__ hend,
                        float* __restrict__ sstart) {
  int idx = blockIdx.x * 256 + threadIdx.x;
  if (idx >= 16384) return;
  float s = 0.f;
  for (int c = 0; c < NCH; ++c) {
    size_t o = (size_t)c * 16384 + idx;
    sstart[o] = s;
    s = fmaf(aprod[o], s, hend[o]);
  }
}

// ---------------- merge done via atomics; LN(128) + silu(z) gate (in-place ym->g) ----------------
__global__ __launch_bounds__(128) void k_merge(const float* __restrict__ ympre,
                                               const float* __restrict__ z,
                                               const float* __restrict__ on_g,
                                               const float* __restrict__ on_b,
                                               float* __restrict__ g) {
  int p = blockIdx.x & (HW - 1), b = blockIdx.x >> 12;
  int d = threadIdx.x;
  float v = ympre[((size_t)b * HW + p) * 128 + d];
  float s = v, sq = v * v;
#pragma unroll
  for (int off = 32; off; off >>= 1) { s += __shfl_xor(s, off); sq += __shfl_xor(sq, off); }
  __shared__ float sh[4];
  if ((threadIdx.x & 63) == 0) { sh[(threadIdx.x >> 6) * 2] = s; sh[(threadIdx.x >> 6) * 2 + 1] = sq; }
  __syncthreads();
  float S = sh[0] + sh[2], SQ = sh[1] + sh[3];
  float mu = S * (1.f / 128.f);
  float var = SQ * (1.f / 128.f) - mu * mu;
  float rs = rsqrtf(var + 1e-5f);
  float gn = (v - mu) * rs * on_g[d] + on_b[d];
  float zv = z[((size_t)(b * 128 + d)) * HW + p];
  float sil = zv / (1.f + __expf(-zv));
  g[((size_t)b * HW + p) * 128 + d] = gn * sil;
}

// ---------------- out proj + layerscale1 residual ----------------
__global__ __launch_bounds__(256) void k_outproj(const float* __restrict__ g,
                                                 const float* __restrict__ out_w,
                                                 const float* __restrict__ t,
                                                 const float* __restrict__ ls1_w,
                                                 const float* __restrict__ ls1_b,
                                                 float* __restrict__ t1) {
  __shared__ float lw[4 * 128];
  int cg = blockIdx.y & 15, b = blockIdx.y >> 4;
  int c0 = cg * 4;
  for (int i = threadIdx.x; i < 512; i += 256) lw[i] = out_w[c0 * 128 + i];
  __syncthreads();
  int p = blockIdx.x * 256 + threadIdx.x;
  const float* gr = g + ((size_t)b * HW + p) * 128;
  float acc[4] = {0, 0, 0, 0};
#pragma unroll 4
  for (int dd = 0; dd < 128; ++dd) {
    float x = gr[dd];
#pragma unroll
    for (int u = 0; u < 4; ++u) acc[u] = fmaf(lw[u * 128 + dd], x, acc[u]);
  }
#pragma unroll
  for (int u = 0; u < 4; ++u) {
    int co = c0 + u;
    size_t o = (size_t)(b * 64 + co) * HW + p;
    t1[o] = fmaf(t[o], ls1_w[co], ls1_b[co]) + acc[u];
  }
}

// ---------------- mlp f1 + exact gelu ----------------
__global__ __launch_bounds__(256) void k_f1(const float* __restrict__ xln2,
                                            const float* __restrict__ f1_w,
                                            const float* __restrict__ f1_b,
                                            float* __restrict__ u1) {
  __shared__ float lw[8 * 64];
  int cg = blockIdx.y & 31, b = blockIdx.y >> 5;
  int c0 = cg * 8;
  for (int i = threadIdx.x; i < 512; i += 256) lw[i] = f1_w[c0 * 64 + i];
  __syncthreads();
  int p = blockIdx.x * 256 + threadIdx.x;
  const float* ib = xln2 + (size_t)b * 64 * HW + p;
  float acc[8] = {0, 0, 0, 0, 0, 0, 0, 0};
#pragma unroll 8
  for (int ci = 0; ci < 64; ++ci) {
    float x = ib[ci * HW];
#pragma unroll
    for (int u = 0; u < 8; ++u) acc[u] = fmaf(lw[u * 64 + ci], x, acc[u]);
  }
#pragma unroll
  for (int u = 0; u < 8; ++u) {
    float v = acc[u] + f1_b[c0 + u];
    v = 0.5f * v * (1.f + erff(v * 0.70710678118654752440f));
    u1[(size_t)(b * 256 + c0 + u) * HW + p] = v;
  }
}

// ---------------- mlp f2 + layerscale2 residual + duplicated output ----------------
__global__ __launch_bounds__(256) void k_f2(const float* __restrict__ u1,
                                            const float* __restrict__ f2_w,
                                            const float* __restrict__ f2_b,
                                            const float* __restrict__ t1,
                                            const float* __restrict__ ls2_w,
                                            const float* __restrict__ ls2_b,
                                            float* __restrict__ out) {
  __shared__ float lw[4 * 256];
  int cg = blockIdx.y & 15, b = blockIdx.y >> 4;
  int c0 = cg * 4;
  for (int i = threadIdx.x; i < 1024; i += 256) lw[i] = f2_w[c0 * 256 + i];
  __syncthreads();
  int p = blockIdx.x * 256 + threadIdx.x;
  const float* ib = u1 + (size_t)b * 256 * HW + p;
  float acc[4] = {0, 0, 0, 0};
#pragma unroll 4
  for (int ci = 0; ci < 256; ++ci) {
    float x = ib[(size_t)ci * HW];
#pragma unroll
    for (int u = 0; u < 4; ++u) acc[u] = fmaf(lw[u * 256 + ci], x, acc[u]);
  }
#pragma unroll
  for (int u = 0; u < 4; ++u) {
    int co = c0 + u;
    size_t o = (size_t)(b * 64 + co) * HW + p;
    float v = fmaf(t1[o], ls2_w[co], ls2_b[co]) + acc[u] + f2_b[co];
    out[o] = v;
    out[o + (size_t)B2 * 64 * HW] = v;
  }
}

extern "C" void kernel_launch(void* const* d_in, const int* in_sizes, int n_in,
                              void* d_out, int out_size, void* d_ws, size_t ws_size,
                              hipStream_t stream) {
  const float* x     = (const float*)d_in[0];
  const float* res   = (const float*)d_in[1];
  const float* smf   = (const float*)d_in[2];
  const float* rc0_w = (const float*)d_in[3];
  const float* rcp_w = (const float*)d_in[4];
  const float* rcp_g = (const float*)d_in[5];
  const float* rcp_b = (const float*)d_in[6];
  const float* pe_w  = (const float*)d_in[7];
  const float* pe_b  = (const float*)d_in[8];
  const float* n1_g  = (const float*)d_in[9];
  const float* n1_b  = (const float*)d_in[10];
  const float* n2_g  = (const float*)d_in[11];
  const float* n2_b  = (const float*)d_in[12];
  const float* q_w   = (const float*)d_in[13];
  const float* q_b   = (const float*)d_in[14];
  const float* sr_w  = (const float*)d_in[15];
  const float* sr_b  = (const float*)d_in[16];
  const float* srn_g = (const float*)d_in[17];
  const float* srn_b = (const float*)d_in[18];
  const float* k_w   = (const float*)d_in[19];
  const float* k_b   = (const float*)d_in[20];
  const float* v_w   = (const float*)d_in[21];
  const float* v_b   = (const float*)d_in[22];
  const float* mp_w  = (const float*)d_in[23];
  const float* mp_b  = (const float*)d_in[24];
  const float* in_w  = (const float*)d_in[25];
  const float* cv_w  = (const float*)d_in[26];
  const float* cv_b  = (const float*)d_in[27];
  const float* xp_w  = (const float*)d_in[28];
  const float* dtp_w = (const float*)d_in[29];
  const float* dtp_b = (const float*)d_in[30];
  const float* Alog  = (const float*)d_in[31];
  const float* Dsk   = (const float*)d_in[32];
  const float* on_g  = (const float*)d_in[33];
  const float* on_b  = (const float*)d_in[34];
  const float* out_w = (const float*)d_in[35];
  const float* ls1_w = (const float*)d_in[36];
  const float* ls1_b = (const float*)d_in[37];
  const float* ls2_w = (const float*)d_in[38];
  const float* ls2_b = (const float*)d_in[39];
  const float* f1_w  = (const float*)d_in[40];
  const float* f1_b  = (const float*)d_in[41];
  const float* f2_w  = (const float*)d_in[42];
  const float* f2_b  = (const float*)d_in[43];
  float* ws = (float*)d_ws;
  float* out = (float*)d_out;

  hipMemsetAsync(ws + OFF_RSHUF, 0, (size_t)B2 * RS_B * sizeof(float), stream);
  k_rconv0<<<dim3(2112), dim3(256), 0, stream>>>(res, rc0_w, ws + OFF_RSHUF);
  k_rconv3<<<dim3(16, 44), dim3(256), 0, stream>>>(ws + OFF_RSHUF, rcp_w, rcp_g, rcp_b, ws + OFF_SHORT);
  k_up<<<dim3(4096), dim3(256), 0, stream>>>(smf, x, ws + OFF_SHORT, ws + OFF_INP);
  k_pe<<<dim3(2048), dim3(256), 0, stream>>>(ws + OFF_INP, pe_w, pe_b, ws + OFF_T);
  k_lnc64<<<dim3(128), dim3(256), 0, stream>>>(ws + OFF_T, n1_g, n1_b, ws + OFF_XLN);
  k_sr<<<dim3(4, 52), dim3(256), 0, stream>>>(ws + OFF_SHORT, sr_w, sr_b, ws + OFF_SRAW);
  k_ln130<<<dim3(2048), dim3(64), 0, stream>>>(ws + OFF_SRAW, srn_g, srn_b, ws + OFF_SRED);
  k_kv<<<dim3(1024), dim3(256), 0, stream>>>(ws + OFF_SRED, k_w, k_b, v_w, v_b, ws + OFF_KT, ws + OFF_VT);
  k_q<<<dim3(2048), dim3(256), 0, stream>>>(ws + OFF_XLN, q_w, q_b, ws + OFF_QT);
  k_attn1<<<dim3(8, 16, 8), dim3(256), 0, stream>>>(ws + OFF_QT, ws + OFF_KT, ws + OFF_VT, ws + OFF_PART);
  k_attn2<<<dim3(128), dim3(256), 0, stream>>>(ws + OFF_PART, ws + OFF_OT);
  k_mp<<<dim3(2048), dim3(256), 0, stream>>>(ws + OFF_OT, mp_w, mp_b, ws + OFF_M0);
  k_inproj<<<dim3(16, 128), dim3(256), 0, stream>>>(ws + OFF_M0, in_w, ws + OFF_XC, ws + OFF_Z);
  k_dw<<<dim3(4096), dim3(256), 0, stream>>>(ws + OFF_XC, cv_w, cv_b, ws + OFF_XC2);
  k_tr<<<dim3(4096), dim3(256), 0, stream>>>(ws + OFF_XC2, ws + OFF_XC2T);
  k_projs<<<dim3(16, 48), dim3(256), 0, stream>>>(ws + OFF_XC2, ws + OFF_XC2T, xp_w, ws + OFF_PROJ);
  k_scan2<0><<<dim3(64, 2, 8), dim3(256), 0, stream>>>(ws + OFF_PROJ, ws + OFF_XC2, ws + OFF_XC2T,
      dtp_w, dtp_b, Alog, Dsk, ws + OFF_APROD, ws + OFF_HEND, ws + OFF_SSTART, ws + OFF_YM);
  k_scanB<<<dim3(64), dim3(256), 0, stream>>>(ws + OFF_APROD, ws + OFF_HEND, ws + OFF_SSTART);
  hipMemsetAsync(ws + OFF_YM, 0, (size_t)B2 * HW * 128 * sizeof(float), stream);
  k_scan2<1><<<dim3(64, 2, 8), dim3(256), 0, stream>>>(ws + OFF_PROJ, ws + OFF_XC2, ws + OFF_XC2T,
      dtp_w, dtp_b, Alog, Dsk, ws + OFF_APROD, ws + OFF_HEND, ws + OFF_SSTART, ws + OFF_YM);
  k_merge<<<dim3(8192), dim3(128), 0, stream>>>(ws + OFF_YM, ws + OFF_Z, on_g, on_b, ws + OFF_YM);
  k_outproj<<<dim3(16, 32), dim3(256), 0, stream>>>(ws + OFF_YM, out_w, ws + OFF_T, ls1_w, ls1_b, ws + OFF_T1);
  k_lnc64<<<dim3(128), dim3(256), 0, stream>>>(ws + OFF_T1, n2_g, n2_b, ws + OFF_XLN);
  k_f1<<<dim3(16, 64), dim3(256), 0, stream>>>(ws + OFF_XLN, f1_w, f1_b, ws + OFF_U1);
  k_f2<<<dim3(16, 32), dim3(256), 0, stream>>>(ws + OFF_U1, f2_w, f2_b, ws + OFF_T1, ls2_w, ls2_b, out);
}